// Round 5
// baseline (364.459 us; speedup 1.0000x reference)
//
#include <hip/hip_runtime.h>
#include <hip/hip_bf16.h>
#include <cstdint>

#define BATCH 8192
#define DIM   128
#define MARGIN 1.0f

typedef __attribute__((ext_vector_type(8))) short short8;
typedef __attribute__((ext_vector_type(4))) float f32x4;
typedef __attribute__((ext_vector_type(4))) int   i32x4;

// ---------------------------------------------------------------------------
// Kernel 1: fp32 -> bf16 convert, per-row squared norms (fp32-exact),
// init hp2 (max-accum, 0) / hn2 (min-accum, +inf) / tail counter.
// ---------------------------------------------------------------------------
__global__ __launch_bounds__(256) void bhtl_prep(
    const float* __restrict__ emb,
    __hip_bfloat16* __restrict__ Ebf,
    float* __restrict__ sq,
    unsigned* __restrict__ hp2,
    unsigned* __restrict__ hn2,
    unsigned* __restrict__ counter)
{
    const int w   = threadIdx.x >> 6;
    const int l   = threadIdx.x & 63;
    const int row = blockIdx.x * 4 + w;
    const float2 e = ((const float2*)(emb + row * DIM))[l];
    __hip_bfloat162 h2;
    h2.x = __float2bfloat16(e.x);
    h2.y = __float2bfloat16(e.y);
    ((__hip_bfloat162*)(Ebf + row * DIM))[l] = h2;
    float s = e.x * e.x + e.y * e.y;
    #pragma unroll
    for (int d = 1; d < 64; d <<= 1) s += __shfl_xor(s, d, 64);
    if (l == 0) {
        sq[row]  = s;
        hp2[row] = 0u;           // max accumulator (non-negative domain)
        hn2[row] = 0x7F800000u;  // +inf (min accumulator)
    }
    if (blockIdx.x == 0 && threadIdx.x == 0) *counter = 0u;
}

// ---------------------------------------------------------------------------
// Kernel 2: fused E @ E^T + hardest-pos/neg + tail-block loss.
// 4096 blocks = 64x64 grid of 128x128 output tiles, 256 threads (4 waves).
// B tile staged once in LDS (bf16, stride 136: 2-way bank alias only = free);
// A fragments in registers (transposed MFMA layout, validated R4:
//   acc = mfma(bf, af): lane(q,ln) elem r -> col j = colbase+n*16+q*4+r,
//                                            row i = rowbase+m*16+ln).
// ONE barrier per block; 4 blocks/CU resident overlap each other's drains.
// Epilogue: val = sq_j - 2*dot, label-select max/min, q-shuffle, atomics.
// Last block (fence+counter) reads hp2/hn2 via atomic-reads, writes loss.
// ---------------------------------------------------------------------------
__global__ __launch_bounds__(256, 4) void bhtl_main(
    const __hip_bfloat16* __restrict__ Ebf,
    const float* __restrict__ sq,
    const int* __restrict__ labels,
    unsigned* __restrict__ hp2,
    unsigned* __restrict__ hn2,
    unsigned* __restrict__ counter,
    float* __restrict__ out)
{
    __shared__ __align__(16) unsigned short B_s[128 * 136];
    __shared__ float red_s[4];
    __shared__ int   flag_s;

    const int tid  = threadIdx.x;
    const int w    = tid >> 6;
    const int lane = tid & 63;
    const int q    = lane >> 4;
    const int ln   = lane & 15;
    const int rt   = blockIdx.x >> 6;
    const int ct   = blockIdx.x & 63;
    const int rowbase = rt * 128 + w * 32;
    const int colbase = ct * 128;

    // ---- stage B tile: thread t -> col c = t>>1, half h = t&1 (128 B) ----
    {
        const int c = tid >> 1, h = tid & 1;
        const __hip_bfloat16* src = Ebf + (colbase + c) * DIM + h * 64;
        unsigned short* dst = &B_s[c * 136 + h * 64];
        #pragma unroll
        for (int u = 0; u < 8; ++u)
            *(uint4*)(dst + u * 8) = *(const uint4*)(src + u * 8);
    }

    // ---- A fragments (32 rows/wave, K=128) + row metadata ----
    short8 af[2][4];
    float  sqi[2];
    int    labi[2];
    #pragma unroll
    for (int m = 0; m < 2; ++m) {
        const int row = rowbase + m * 16 + ln;
        #pragma unroll
        for (int kc = 0; kc < 4; ++kc)
            af[m][kc] = *(const short8*)(Ebf + row * DIM + kc * 32 + q * 8);
        sqi[m]  = sq[row];
        labi[m] = labels[row];
    }

    float mp[2] = {-INFINITY, -INFINITY};
    float mn[2] = { INFINITY,  INFINITY};

    __syncthreads();

    #pragma unroll 2
    for (int n = 0; n < 8; ++n) {
        short8 bfr[4];
        #pragma unroll
        for (int kc = 0; kc < 4; ++kc)
            bfr[kc] = *(const short8*)(&B_s[(n * 16 + ln) * 136 + kc * 32 + q * 8]);
        f32x4 sqj  = *(const f32x4*)(sq     + colbase + n * 16 + q * 4);
        i32x4 labj = *(const i32x4*)(labels + colbase + n * 16 + q * 4);

        f32x4 acc[2];
        const f32x4 zero = {0.f, 0.f, 0.f, 0.f};
        acc[0] = zero; acc[1] = zero;
        #pragma unroll
        for (int kc = 0; kc < 4; ++kc)
            #pragma unroll
            for (int m = 0; m < 2; ++m)
                acc[m] = __builtin_amdgcn_mfma_f32_16x16x32_bf16(
                    bfr[kc], af[m][kc], acc[m], 0, 0, 0);

        #pragma unroll
        for (int m = 0; m < 2; ++m)
            #pragma unroll
            for (int r = 0; r < 4; ++r) {
                float val = fmaf(-2.0f, acc[m][r], sqj[r]);
                bool same = (labi[m] == labj[r]);
                mp[m] = fmaxf(mp[m], same ? val : -INFINITY);
                mn[m] = fminf(mn[m], same ? INFINITY : val);
            }
    }

    // ---- reduce over the 4 q-lanes sharing each row, then atomics ----
    #pragma unroll
    for (int m = 0; m < 2; ++m) {
        float a = mp[m], b = mn[m];
        a = fmaxf(a, __shfl_xor(a, 16, 64));
        a = fmaxf(a, __shfl_xor(a, 32, 64));
        b = fminf(b, __shfl_xor(b, 16, 64));
        b = fminf(b, __shfl_xor(b, 32, 64));
        if (q == 0) {
            const int row = rowbase + m * 16 + ln;
            atomicMax(&hp2[row], __float_as_uint(fmaxf(sqi[m] + a, 0.0f)));
            atomicMin(&hn2[row], __float_as_uint(fmaxf(sqi[m] + b, 0.0f)));
        }
    }

    // ---- tail block: last to finish computes the loss ----
    __threadfence();
    if (tid == 0) {
        unsigned old = atomicAdd(counter, 1u);
        flag_s = (old == (unsigned)(gridDim.x - 1)) ? 1 : 0;
    }
    __syncthreads();
    if (!flag_s) return;
    __threadfence();

    float sum = 0.f;
    for (int i = tid; i < BATCH; i += 256) {
        unsigned hb = atomicMax(&hp2[i], 0u);            // pure read
        unsigned nb = atomicMin(&hn2[i], 0x7F800000u);   // pure read
        float hp = sqrtf(__uint_as_float(hb));
        float hn = sqrtf(__uint_as_float(nb));
        sum += fmaxf(hp - hn + MARGIN, 0.f);
    }
    #pragma unroll
    for (int d = 1; d < 64; d <<= 1) sum += __shfl_xor(sum, d, 64);
    if (lane == 0) red_s[w] = sum;
    __syncthreads();
    if (tid == 0)
        out[0] = (red_s[0] + red_s[1] + red_s[2] + red_s[3]) / (float)BATCH;
}

// ---------------------------------------------------------------------------
extern "C" void kernel_launch(void* const* d_in, const int* in_sizes, int n_in,
                              void* d_out, int out_size, void* d_ws, size_t ws_size,
                              hipStream_t stream)
{
    const float* emb    = (const float*)d_in[0];
    const int*   labels = (const int*)d_in[1];
    float*       out    = (float*)d_out;

    char* ws = (char*)d_ws;
    __hip_bfloat16* Ebf = (__hip_bfloat16*)ws;                        // 2 MiB
    float*    sq   = (float*)   (ws + 2 * 1024 * 1024);               // 32 KiB
    unsigned* hp2  = (unsigned*)(ws + 2 * 1024 * 1024 + 32 * 1024);   // 32 KiB
    unsigned* hn2  = (unsigned*)(ws + 2 * 1024 * 1024 + 64 * 1024);   // 32 KiB
    unsigned* cnt  = (unsigned*)(ws + 2 * 1024 * 1024 + 96 * 1024);   // 4 B

    bhtl_prep<<<BATCH / 4, 256, 0, stream>>>(emb, Ebf, sq, hp2, hn2, cnt);
    bhtl_main<<<4096, 256, 0, stream>>>(Ebf, sq, labels, hp2, hn2, cnt, out);
}

// Round 6
// 89.052 us; speedup vs baseline: 4.0926x; 4.0926x over previous
//
#include <hip/hip_runtime.h>
#include <hip/hip_bf16.h>
#include <cstdint>

#define BATCH 8192
#define DIM   128
#define MARGIN 1.0f

typedef __attribute__((ext_vector_type(8))) short short8;
typedef __attribute__((ext_vector_type(4))) float f32x4;
typedef __attribute__((ext_vector_type(4))) int   i32x4;

// async 16B global -> LDS (no VGPR destination; LDS dst = wave-uniform base + lane*16)
__device__ __forceinline__ void async_copy16(const __hip_bfloat16* g, unsigned short* lds) {
    __builtin_amdgcn_global_load_lds(
        (const __attribute__((address_space(1))) unsigned int*)g,
        (__attribute__((address_space(3))) unsigned int*)lds, 16, 0, 0);
}

// ---------------------------------------------------------------------------
// Kernel 1: fp32 -> bf16 convert, per-row squared norms (fp32-exact),
// init hp2 (max-accum, 0) / hn2 (min-accum, +inf).
// ---------------------------------------------------------------------------
__global__ __launch_bounds__(256) void bhtl_prep(
    const float* __restrict__ emb,
    __hip_bfloat16* __restrict__ Ebf,
    float* __restrict__ sq,
    unsigned* __restrict__ hp2,
    unsigned* __restrict__ hn2)
{
    const int w   = threadIdx.x >> 6;
    const int l   = threadIdx.x & 63;
    const int row = blockIdx.x * 4 + w;
    const float2 e = ((const float2*)(emb + row * DIM))[l];
    __hip_bfloat162 h2;
    h2.x = __float2bfloat16(e.x);
    h2.y = __float2bfloat16(e.y);
    ((__hip_bfloat162*)(Ebf + row * DIM))[l] = h2;
    float s = e.x * e.x + e.y * e.y;
    #pragma unroll
    for (int d = 1; d < 64; d <<= 1) s += __shfl_xor(s, d, 64);
    if (l == 0) {
        sq[row]  = s;
        hp2[row] = 0u;           // max accumulator (non-negative domain)
        hn2[row] = 0x7F800000u;  // +inf (min accumulator)
    }
}

// ---------------------------------------------------------------------------
// Kernel 2: fused E @ E^T + hardest-pos/neg selection (m97-style staging).
// 512 blocks = 64 row-tiles x 8 col-splits, 256 threads (4 waves).
// Per block: 128 rows x 1024 cols, as 8 chunks of 128 cols.
// B chunks double-buffered in LDS (32 KB each) via global_load_lds width=16.
//   XOR swizzle on the GLOBAL side (LDS dst must be base+lane*16, no pad):
//   LDS unit (col, u) holds global 16B-chunk j = u ^ (col & 7) of column col.
//   Fragment ds_read_b128 at unit (kc*4+q)^(ln&7) -> 8-deep banks = minimum.
// A fragments in registers (transposed MFMA: acc = mfma(B, A) so lane (q,ln)
//   elem r -> row = rowbase+m*16+ln, col = jb+n*16+q*4+r; validated R4/R5).
// One barrier per chunk (9 total). Atomics fire-and-forget, NO fence.
// ---------------------------------------------------------------------------
__global__ __launch_bounds__(256) void bhtl_main(
    const __hip_bfloat16* __restrict__ Ebf,
    const float* __restrict__ sq,
    const int* __restrict__ labels,
    unsigned* __restrict__ hp2,
    unsigned* __restrict__ hn2)
{
    __shared__ __align__(16) unsigned short B_s[2][16384];   // 2 x 32 KB

    const int tid  = threadIdx.x;
    const int w    = tid >> 6;
    const int lane = tid & 63;
    const int q    = lane >> 4;
    const int ln   = lane & 15;
    const int rt   = blockIdx.x >> 3;          // 0..63 row tile
    const int js   = blockIdx.x & 7;           // 0..7 col split
    const int rowbase = rt * 128 + w * 32;
    const int jbase0  = js * 1024;

    // ---- staging helper: wave w stages units [w*512, w*512+512) of a chunk ----
    const int ubase = w * 512 + lane;          // this lane's first unit (stride 64)
    auto stage = [&](int buf, int chunk) {
        const int jb = jbase0 + chunk * 128;
        #pragma unroll
        for (int c = 0; c < 8; ++c) {
            int U   = ubase + c * 64;          // unit index in chunk (16B units)
            int col = U >> 4;                  // 0..127
            int u   = U & 15;
            int j   = u ^ (col & 7);           // swizzled source 16B-chunk
            async_copy16(Ebf + (size_t)(jb + col) * DIM + j * 8,
                         &B_s[buf][(w * 512 + c * 64) * 8]);
        }
    };

    // ---- A fragments (32 rows/wave, K=128) + row metadata ----
    short8 af[2][4];
    float  sqi[2];
    int    labi[2];
    #pragma unroll
    for (int m = 0; m < 2; ++m) {
        const int row = rowbase + m * 16 + ln;
        #pragma unroll
        for (int kc = 0; kc < 4; ++kc)
            af[m][kc] = *(const short8*)(Ebf + (size_t)row * DIM + kc * 32 + q * 8);
        sqi[m]  = sq[row];
        labi[m] = labels[row];
    }

    float mp[2] = {-INFINITY, -INFINITY};
    float mn[2] = { INFINITY,  INFINITY};

    stage(0, 0);
    __syncthreads();                           // chunk 0 staged

    #pragma unroll 2
    for (int ch = 0; ch < 8; ++ch) {
        const int buf = ch & 1;
        if (ch < 7) stage(buf ^ 1, ch + 1);    // prefetch next chunk (other buffer)

        const int jb = jbase0 + ch * 128;
        #pragma unroll
        for (int n = 0; n < 8; ++n) {
            short8 bfr[4];
            #pragma unroll
            for (int kc = 0; kc < 4; ++kc)
                bfr[kc] = *(const short8*)(
                    &B_s[buf][(n * 16 + ln) * 128 + (((kc * 4 + q) ^ (ln & 7)) << 3)]);
            f32x4 sqj  = *(const f32x4*)(sq     + jb + n * 16 + q * 4);
            i32x4 labj = *(const i32x4*)(labels + jb + n * 16 + q * 4);

            f32x4 acc[2];
            const f32x4 zero = {0.f, 0.f, 0.f, 0.f};
            acc[0] = zero; acc[1] = zero;
            #pragma unroll
            for (int kc = 0; kc < 4; ++kc)
                #pragma unroll
                for (int m = 0; m < 2; ++m)
                    acc[m] = __builtin_amdgcn_mfma_f32_16x16x32_bf16(
                        bfr[kc], af[m][kc], acc[m], 0, 0, 0);   // transposed

            #pragma unroll
            for (int m = 0; m < 2; ++m)
                #pragma unroll
                for (int r = 0; r < 4; ++r) {
                    float val = fmaf(-2.0f, acc[m][r], sqj[r]);
                    bool same = (labi[m] == labj[r]);
                    mp[m] = fmaxf(mp[m], same ? val : -INFINITY);
                    mn[m] = fminf(mn[m], same ? INFINITY : val);
                }
        }
        __syncthreads();   // staging of ch+1 complete; all waves done reading buf
    }

    // ---- reduce over the 4 q-lanes sharing each row, then atomics ----
    #pragma unroll
    for (int m = 0; m < 2; ++m) {
        float a = mp[m], b = mn[m];
        a = fmaxf(a, __shfl_xor(a, 16, 64));
        a = fmaxf(a, __shfl_xor(a, 32, 64));
        b = fminf(b, __shfl_xor(b, 16, 64));
        b = fminf(b, __shfl_xor(b, 32, 64));
        if (q == 0) {
            const int row = rowbase + m * 16 + ln;
            atomicMax(&hp2[row], __float_as_uint(fmaxf(sqi[m] + a, 0.0f)));
            atomicMin(&hn2[row], __float_as_uint(fmaxf(sqi[m] + b, 0.0f)));
        }
    }
}

// ---------------------------------------------------------------------------
// Kernel 3: per-anchor loss + mean. Single block, deterministic output.
// ---------------------------------------------------------------------------
__global__ __launch_bounds__(1024) void bhtl_final(
    const unsigned* __restrict__ hp2,
    const unsigned* __restrict__ hn2,
    float* __restrict__ out)
{
    __shared__ float red[16];
    float sum = 0.f;
    for (int i = threadIdx.x; i < BATCH; i += 1024) {
        float hp = sqrtf(__uint_as_float(hp2[i]));
        float hn = sqrtf(__uint_as_float(hn2[i]));
        sum += fmaxf(hp - hn + MARGIN, 0.f);
    }
    #pragma unroll
    for (int d = 1; d < 64; d <<= 1) sum += __shfl_xor(sum, d, 64);
    int wv = threadIdx.x >> 6;
    if ((threadIdx.x & 63) == 0) red[wv] = sum;
    __syncthreads();
    if (threadIdx.x < 64) {
        float v = (threadIdx.x < 16) ? red[threadIdx.x] : 0.f;
        #pragma unroll
        for (int d = 1; d < 16; d <<= 1) v += __shfl_xor(v, d, 64);
        if (threadIdx.x == 0) out[0] = v / (float)BATCH;
    }
}

// ---------------------------------------------------------------------------
extern "C" void kernel_launch(void* const* d_in, const int* in_sizes, int n_in,
                              void* d_out, int out_size, void* d_ws, size_t ws_size,
                              hipStream_t stream)
{
    const float* emb    = (const float*)d_in[0];
    const int*   labels = (const int*)d_in[1];
    float*       out    = (float*)d_out;

    char* ws = (char*)d_ws;
    __hip_bfloat16* Ebf = (__hip_bfloat16*)ws;                        // 2 MiB
    float*    sq   = (float*)   (ws + 2 * 1024 * 1024);               // 32 KiB
    unsigned* hp2  = (unsigned*)(ws + 2 * 1024 * 1024 + 32 * 1024);   // 32 KiB
    unsigned* hn2  = (unsigned*)(ws + 2 * 1024 * 1024 + 64 * 1024);   // 32 KiB

    bhtl_prep<<<BATCH / 4, 256, 0, stream>>>(emb, Ebf, sq, hp2, hn2);
    bhtl_main<<<512, 256, 0, stream>>>(Ebf, sq, labels, hp2, hn2);
    bhtl_final<<<1, 1024, 0, stream>>>(hp2, hn2, out);
}